// Round 1
// baseline (238.667 us; speedup 1.0000x reference)
//
#include <hip/hip_runtime.h>
#include <math.h>

#define DIM   1024
#define NROWS 32768

// One 256-thread block owns a full 1024-wide row slice: thread tid handles
// dims [4*tid, 4*tid+4). Its 7 coeffs/dim (28 floats) are loaded ONCE into
// registers and reused across the grid-stride loop over rows — zero
// per-element coefficient traffic.
__global__ __launch_bounds__(256) void fourier_kan_kernel(
    const float* __restrict__ x, const float* __restrict__ coeffs,
    float* __restrict__ out, int n_rows)
{
    const int tid = threadIdx.x;
    const int d0  = tid * 4;

    // coeff layout per d: [c0, cs1, cc1, cs2, cc2, cs3, cc3]
    float cc0[4], cs1[4], cc1[4], cs2[4], cc2[4], cs3[4], cc3[4];
#pragma unroll
    for (int j = 0; j < 4; ++j) {
        const float* cp = coeffs + (size_t)(d0 + j) * 7;
        cc0[j] = cp[0];
        cs1[j] = cp[1]; cc1[j] = cp[2];
        cs2[j] = cp[3]; cc2[j] = cp[4];
        cs3[j] = cp[5]; cc3[j] = cp[6];
    }

    for (int t = blockIdx.x; t < n_rows; t += gridDim.x) {
        const size_t base = (size_t)t * DIM + d0;
        const float4 xv = *reinterpret_cast<const float4*>(x + base);
        float xin[4] = {xv.x, xv.y, xv.z, xv.w};
        float o[4];
#pragma unroll
        for (int j = 0; j < 4; ++j) {
            float s1, c1;
            __sincosf(xin[j], &s1, &c1);          // native v_sin/v_cos path
            const float s2 = 2.0f * s1 * c1;      // sin(2x)
            const float c2 = 1.0f - 2.0f * s1 * s1; // cos(2x)
            const float s3 = s2 * c1 + c2 * s1;   // sin(3x)
            const float c3 = c2 * c1 - s2 * s1;   // cos(3x)
            float corr = cc0[j];
            corr = fmaf(s1, cs1[j], corr);
            corr = fmaf(c1, cc1[j], corr);
            corr = fmaf(s2, cs2[j], corr);
            corr = fmaf(c2, cc2[j], corr);
            corr = fmaf(s3, cs3[j], corr);
            corr = fmaf(c3, cc3[j], corr);
            o[j] = xin[j] + corr;
        }
        float4 ov = {o[0], o[1], o[2], o[3]};
        *reinterpret_cast<float4*>(out + base) = ov;
    }
}

extern "C" void kernel_launch(void* const* d_in, const int* in_sizes, int n_in,
                              void* d_out, int out_size, void* d_ws, size_t ws_size,
                              hipStream_t stream) {
    const float* x      = (const float*)d_in[0];
    const float* coeffs = (const float*)d_in[1];
    float* out          = (float*)d_out;
    (void)in_sizes; (void)n_in; (void)out_size; (void)d_ws; (void)ws_size;

    // 4096 blocks -> each block walks 8 rows; coeff register-load amortized 8x.
    const int grid = 4096;
    fourier_kan_kernel<<<grid, 256, 0, stream>>>(x, coeffs, out, NROWS);
}

// Round 2
// 232.849 us; speedup vs baseline: 1.0250x; 1.0250x over previous
//
#include <hip/hip_runtime.h>
#include <math.h>

#define DIM   1024
#define NROWS 32768
#define RUNROLL 4   // rows per loop iteration (memory-level parallelism)

// One 256-thread block owns a full 1024-wide row slice: thread tid handles
// dims [4*tid, 4*tid+4). Its 28 coeffs load once as 7 float4s and live in
// registers for every row. Main loop batches RUNROLL rows: all loads issued
// back-to-back before any compute -> 4 outstanding 16B loads/thread.
__global__ __launch_bounds__(256) void fourier_kan_kernel(
    const float* __restrict__ x, const float* __restrict__ coeffs,
    float* __restrict__ out, int n_rows)
{
    const int tid = threadIdx.x;
    const int d0  = tid * 4;

    // coeff layout per d: [c0, cs1, cc1, cs2, cc2, cs3, cc3]; this thread's
    // 4 dims are 28 contiguous floats starting at 28*tid (16B aligned).
    float cbuf[28];
    const float4* cp4 = reinterpret_cast<const float4*>(coeffs + (size_t)tid * 28);
#pragma unroll
    for (int i = 0; i < 7; ++i)
        reinterpret_cast<float4*>(cbuf)[i] = cp4[i];

    for (int t0 = blockIdx.x * RUNROLL; t0 < n_rows; t0 += gridDim.x * RUNROLL) {
        float4 xv[RUNROLL];
#pragma unroll
        for (int r = 0; r < RUNROLL; ++r)
            xv[r] = *reinterpret_cast<const float4*>(x + (size_t)(t0 + r) * DIM + d0);

#pragma unroll
        for (int r = 0; r < RUNROLL; ++r) {
            float xin[4] = {xv[r].x, xv[r].y, xv[r].z, xv[r].w};
            float o[4];
#pragma unroll
            for (int j = 0; j < 4; ++j) {
                float s1, c1;
                __sincosf(xin[j], &s1, &c1);            // native v_sin/v_cos
                const float s2 = 2.0f * s1 * c1;        // sin(2x)
                const float c2 = 1.0f - 2.0f * s1 * s1; // cos(2x)
                const float s3 = s2 * c1 + c2 * s1;     // sin(3x)
                const float c3 = c2 * c1 - s2 * s1;     // cos(3x)
                float corr = cbuf[7 * j + 0];
                corr = fmaf(s1, cbuf[7 * j + 1], corr);
                corr = fmaf(c1, cbuf[7 * j + 2], corr);
                corr = fmaf(s2, cbuf[7 * j + 3], corr);
                corr = fmaf(c2, cbuf[7 * j + 4], corr);
                corr = fmaf(s3, cbuf[7 * j + 5], corr);
                corr = fmaf(c3, cbuf[7 * j + 6], corr);
                o[j] = xin[j] + corr;
            }
            float4 ov = {o[0], o[1], o[2], o[3]};
            *reinterpret_cast<float4*>(out + (size_t)(t0 + r) * DIM + d0) = ov;
        }
    }
}

extern "C" void kernel_launch(void* const* d_in, const int* in_sizes, int n_in,
                              void* d_out, int out_size, void* d_ws, size_t ws_size,
                              hipStream_t stream) {
    const float* x      = (const float*)d_in[0];
    const float* coeffs = (const float*)d_in[1];
    float* out          = (float*)d_out;
    (void)in_sizes; (void)n_in; (void)out_size; (void)d_ws; (void)ws_size;

    // 2048 blocks x 4 rows/iter x 4 iters = 32768 rows exactly.
    const int grid = 2048;
    fourier_kan_kernel<<<grid, 256, 0, stream>>>(x, coeffs, out, NROWS);
}

// Round 4
// 232.046 us; speedup vs baseline: 1.0285x; 1.0035x over previous
//
#include <hip/hip_runtime.h>
#include <math.h>

#define DIM   1024
#define NROWS 32768
#define RPB   8      // rows per block, loop-free: 4096 blocks x 8 rows = 32768

// native clang vector type: valid target for __builtin_nontemporal_store
typedef float v4f __attribute__((ext_vector_type(4)));

// per-element correction: c0 + s1*cs1 + c1*cc1 + s2*cs2 + c2*cc2 + s3*cs3 + c3*cc3
__device__ __forceinline__ float fk_elem(float xin,
    float C0, float S1, float C1, float S2, float C2, float S3, float C3)
{
    float s1, c1;
    __sincosf(xin, &s1, &c1);               // native v_sin/v_cos path
    const float s2 = 2.0f * s1 * c1;        // sin(2x)
    const float c2 = 1.0f - 2.0f * s1 * s1; // cos(2x)
    const float s3 = s2 * c1 + c2 * s1;     // sin(3x)
    const float c3 = c2 * c1 - s2 * s1;     // cos(3x)
    float corr = C0;
    corr = fmaf(s1, S1, corr);
    corr = fmaf(c1, C1, corr);
    corr = fmaf(s2, S2, corr);
    corr = fmaf(c2, C2, corr);
    corr = fmaf(s3, S3, corr);
    corr = fmaf(c3, C3, corr);
    return xin + corr;
}

// Thread tid owns dims [4*tid, 4*tid+4). Its 28 coeffs = 7 contiguous float4s
// at coeffs + 28*tid (112B, 16B-aligned). Loaded into NAMED v4f registers
// (q0..q6) so the compiler cannot sink/spill them. 8 rows loaded up-front as
// named v4fs -> 8 outstanding 16B loads/thread before any compute.
__global__ __launch_bounds__(256) void fourier_kan_kernel(
    const float* __restrict__ x, const float* __restrict__ coeffs,
    float* __restrict__ out)
{
    const int tid = threadIdx.x;
    const int t0  = blockIdx.x * RPB;

    const v4f* cp = reinterpret_cast<const v4f*>(coeffs + (size_t)tid * 28);
    const v4f q0 = cp[0], q1 = cp[1], q2 = cp[2], q3 = cp[3],
              q4 = cp[4], q5 = cp[5], q6 = cp[6];

    const v4f* xr  = reinterpret_cast<const v4f*>(x + (size_t)t0 * DIM) + tid;
    v4f*       orw = reinterpret_cast<v4f*>(out + (size_t)t0 * DIM) + tid;

    // 8 independent loads, issued back-to-back (rows are 256 v4fs apart)
    const v4f x0 = xr[0 * 256], x1 = xr[1 * 256], x2 = xr[2 * 256],
              x3 = xr[3 * 256], x4 = xr[4 * 256], x5 = xr[5 * 256],
              x6 = xr[6 * 256], x7 = xr[7 * 256];

    // flat coeff index 7*j+i for dim j, term i:
    // j=0: q0.x q0.y q0.z q0.w q1.x q1.y q1.z
    // j=1: q1.w q2.x q2.y q2.z q2.w q3.x q3.y
    // j=2: q3.z q3.w q4.x q4.y q4.z q4.w q5.x
    // j=3: q5.y q5.z q5.w q6.x q6.y q6.z q6.w
#define FK_ROW(xv, r)                                                         \
    do {                                                                      \
        v4f ov;                                                               \
        ov.x = fk_elem(xv.x, q0.x, q0.y, q0.z, q0.w, q1.x, q1.y, q1.z);       \
        ov.y = fk_elem(xv.y, q1.w, q2.x, q2.y, q2.z, q2.w, q3.x, q3.y);       \
        ov.z = fk_elem(xv.z, q3.z, q3.w, q4.x, q4.y, q4.z, q4.w, q5.x);       \
        ov.w = fk_elem(xv.w, q5.y, q5.z, q5.w, q6.x, q6.y, q6.z, q6.w);       \
        __builtin_nontemporal_store(ov, orw + (r) * 256);                     \
    } while (0)

    FK_ROW(x0, 0); FK_ROW(x1, 1); FK_ROW(x2, 2); FK_ROW(x3, 3);
    FK_ROW(x4, 4); FK_ROW(x5, 5); FK_ROW(x6, 6); FK_ROW(x7, 7);
#undef FK_ROW
}

extern "C" void kernel_launch(void* const* d_in, const int* in_sizes, int n_in,
                              void* d_out, int out_size, void* d_ws, size_t ws_size,
                              hipStream_t stream) {
    const float* x      = (const float*)d_in[0];
    const float* coeffs = (const float*)d_in[1];
    float* out          = (float*)d_out;
    (void)in_sizes; (void)n_in; (void)out_size; (void)d_ws; (void)ws_size;

    const int grid = NROWS / RPB;  // 4096 blocks, loop-free
    fourier_kan_kernel<<<grid, 256, 0, stream>>>(x, coeffs, out);
}